// Round 5
// baseline (221.573 us; speedup 1.0000x reference)
//
#include <hip/hip_runtime.h>
#include <math.h>

// DynamicHybridRouter via bf16-split MFMA (3-term: xh*wh + xh*wl + xl*wh).
// R5: R4 post-mortem = memory-LATENCY bound (hbm 12.6%, MfmaUtil 6%, occupancy 39.7%
// grid-capped, ~800B in flight/CU vs ~8KB needed). Fix: (1) grid 1024 (BM=16,
// TPB=256, 4 blocks/CU); (2) drop eh-twin (4 expert tiles/wave -> all x loads
// unique); (3) x prefetch ring depth 4 -> 8 b128 loads in flight per wave.

#define NROWS 16384
#define DIM   2048
#define NEXP  64
#define BM    16
#define TPB   256
#define KSLICE 512
#define KSTEPS (KSLICE / 32)   // 16

typedef __attribute__((ext_vector_type(4))) float f32x4;
typedef __attribute__((ext_vector_type(8))) short bf16x8;

// ---- prologue: w [64][2048] f32 -> B-frag-ordered bf16 hi/lo in ws ----
// frag slot = ((kstep*4 + t)*64 + lane): 8 bf16 of w[e=16t+(lane&15)]
// [k = kstep*32 + (lane>>4)*8 + j].  16384 slots x 16B per array.
__global__ void wfrag_kernel(const float* __restrict__ gw,
                             unsigned short* __restrict__ wsH,
                             unsigned short* __restrict__ wsL) {
  int slot  = blockIdx.x * 256 + threadIdx.x;
  int lane  = slot & 63;
  int t     = (slot >> 6) & 3;
  int kstep = slot >> 8;
  int e  = 16 * t + (lane & 15);
  int k0 = kstep * 32 + (lane >> 4) * 8;
  const float* src = gw + (size_t)e * DIM + k0;
  bf16x8 vh, vl;
#pragma unroll
  for (int j = 0; j < 8; ++j) {
    float w = src[j];
    unsigned u = __float_as_uint(w);
    vh[j] = (short)(u >> 16);
    float hi = __uint_as_float(u & 0xffff0000u);
    float rl = w - hi;
    vl[j] = (short)(__float_as_uint(rl) >> 16);
  }
  ((bf16x8*)wsH)[slot] = vh;
  ((bf16x8*)wsL)[slot] = vl;
}

// ---- main kernel ----
__global__ __launch_bounds__(TPB, 4)
void router_mfma(const float* __restrict__ x,
                 const unsigned short* __restrict__ wsH,
                 const unsigned short* __restrict__ wsL,
                 const float* __restrict__ gb,
                 const int* __restrict__ mat,
                 float* __restrict__ out) {
  __shared__ float slab[4 * BM * NEXP];   // 4 K-slice partial slabs (16KB)
  __shared__ float p_a[BM], p_b[BM];
  __shared__ int   p_i[BM], p_j[BM];
  __shared__ int   s_flag;

  const int tid  = threadIdx.x;
  const int ksl  = tid >> 6;     // wave = K-slice 0..3 (512 each)
  const int lane = tid & 63;
  const int m    = lane & 15;
  const int kg   = lane >> 4;
  const int row0 = blockIdx.x * BM;

  if (tid < 64) {
    unsigned long long b = __ballot(mat[lane] == 0);
    if (lane == 0) s_flag = (b != 0ull) ? 1 : 0;
  }

  f32x4 acc[4];
#pragma unroll
  for (int t = 0; t < 4; ++t) acc[t] = (f32x4)0.0f;

  // B-frag base: slot = ((kstep*4 + t)*64 + lane), kstep = ksl*16 + s
  const size_t bbase = (size_t)((ksl * KSTEPS * 4) * 64 + lane);
  const bf16x8* bHp = (const bf16x8*)wsH + bbase;
  const bf16x8* bLp = (const bf16x8*)wsL + bbase;

  const float* xb = x + (size_t)(row0 + m) * DIM + ksl * KSLICE + kg * 8;

  // x prefetch ring, depth 4 (8 b128 loads in flight)
  float4 xr[4][2];
#pragma unroll
  for (int p = 0; p < 4; ++p) {
    xr[p][0] = *(const float4*)(xb + p * 32);
    xr[p][1] = *(const float4*)(xb + p * 32 + 4);
  }

#pragma unroll 4
  for (int s = 0; s < KSTEPS; ++s) {
    const int slot = s & 3;
    // convert current x (landed >=3 steps ago) to hi/lo bf16 A-frags
    bf16x8 ah, al;
#pragma unroll
    for (int q = 0; q < 2; ++q) {
      float4 v = xr[slot][q];
      float ff[4] = {v.x, v.y, v.z, v.w};
#pragma unroll
      for (int j = 0; j < 4; ++j) {
        unsigned u = __float_as_uint(ff[j]);
        ah[q * 4 + j] = (short)(u >> 16);
        float hi = __uint_as_float(u & 0xffff0000u);
        float rl = ff[j] - hi;
        al[q * 4 + j] = (short)(__float_as_uint(rl) >> 16);
      }
    }
    // refill ring slot with step s+4 (clamped re-fetch at the tail, branch-free)
    {
      const int sp = (s + 4 < KSTEPS) ? (s + 4) : s;
      xr[slot][0] = *(const float4*)(xb + sp * 32);
      xr[slot][1] = *(const float4*)(xb + sp * 32 + 4);
    }
    // B frags for this step (L2-resident, coalesced 1KB/instr)
    bf16x8 bh[4], bl[4];
#pragma unroll
    for (int t = 0; t < 4; ++t) {
      bh[t] = bHp[(size_t)s * 256 + t * 64];
      bl[t] = bLp[(size_t)s * 256 + t * 64];
    }
    // 3-term MFMA accumulate over 4 expert tiles
#pragma unroll
    for (int t = 0; t < 4; ++t) {
      acc[t] = __builtin_amdgcn_mfma_f32_16x16x32_bf16(ah, bh[t], acc[t], 0, 0, 0);
      acc[t] = __builtin_amdgcn_mfma_f32_16x16x32_bf16(ah, bl[t], acc[t], 0, 0, 0);
      acc[t] = __builtin_amdgcn_mfma_f32_16x16x32_bf16(al, bh[t], acc[t], 0, 0, 0);
    }
  }

  // ---- partials: slab[ksl][row][expert]; C/D layout col=lane&15, row=kg*4+reg ----
  {
    float* sl = slab + ksl * (BM * NEXP);
#pragma unroll
    for (int t = 0; t < 4; ++t)
#pragma unroll
      for (int reg = 0; reg < 4; ++reg)
        sl[(kg * 4 + reg) * NEXP + 16 * t + m] = acc[t][reg];
  }
  __syncthreads();

  // 4 K-slice slabs + bias -> logits in slab[0..1024)
  for (int idx = tid; idx < BM * NEXP; idx += TPB) {
    float v = slab[idx] + slab[1024 + idx] + slab[2048 + idx] + slab[3072 + idx]
            + gb[idx & (NEXP - 1)];
    slab[idx] = v;
  }
  __syncthreads();

  const int flag = s_flag;

  // per-row routing (threads 0..15; rotated scan spreads LDS banks)
  if (tid < BM) {
    const float* rowp = slab + tid * NEXP;
    if (flag == 0) {
      float m1 = -1e30f, m2 = -1e30f;
      int i1 = 0, i2 = 0;
      for (int ee = 0; ee < NEXP; ++ee) {
        int e = (ee + tid) & (NEXP - 1);
        float v = rowp[e];
        if (v > m1) { m2 = m1; i2 = i1; m1 = v; i1 = e; }
        else if (v > m2) { m2 = v; i2 = e; }
      }
      float t = expf(m2 - m1);
      float pa = 1.0f / (1.0f + t);
      p_a[tid] = pa;
      p_b[tid] = t * pa;
      p_i[tid] = i1;
      p_j[tid] = i2;
    } else {
      float mx = -1e30f;
      for (int ee = 0; ee < NEXP; ++ee)
        mx = fmaxf(mx, rowp[(ee + tid) & (NEXP - 1)]);
      float ssum = 0.0f;
      for (int ee = 0; ee < NEXP; ++ee)
        ssum += expf((rowp[(ee + tid) & (NEXP - 1)] - mx) * 0.5f);  // /T=2
      p_a[tid] = mx;
      p_b[tid] = 1.0f / ssum;
    }
  }
  __syncthreads();

  // output: 16x64 tile = 256 float4, one per thread
  {
    int q  = tid;
    int r  = q >> 4;
    int e0 = (q & 15) * 4;
    float4 v;
    if (flag == 0) {
      int i1 = p_i[r], i2 = p_j[r];
      float a = p_a[r], b = p_b[r];
      v.x = (e0 + 0 == i1) ? a : (e0 + 0 == i2) ? b : 0.0f;
      v.y = (e0 + 1 == i1) ? a : (e0 + 1 == i2) ? b : 0.0f;
      v.z = (e0 + 2 == i1) ? a : (e0 + 2 == i2) ? b : 0.0f;
      v.w = (e0 + 3 == i1) ? a : (e0 + 3 == i2) ? b : 0.0f;
    } else {
      float mx = p_a[r], inv = p_b[r];
      const float* rowp = slab + r * NEXP + e0;
      v.x = expf((rowp[0] - mx) * 0.5f) * inv;
      v.y = expf((rowp[1] - mx) * 0.5f) * inv;
      v.z = expf((rowp[2] - mx) * 0.5f) * inv;
      v.w = expf((rowp[3] - mx) * 0.5f) * inv;
    }
    *(float4*)(out + (size_t)(row0 + r) * NEXP + e0) = v;
  }
}

extern "C" void kernel_launch(void* const* d_in, const int* in_sizes, int n_in,
                              void* d_out, int out_size, void* d_ws, size_t ws_size,
                              hipStream_t stream) {
  const float* x  = (const float*)d_in[0];
  const float* gw = (const float*)d_in[1];
  const float* gb = (const float*)d_in[2];
  const int*   mt = (const int*)d_in[3];
  float* outp = (float*)d_out;
  (void)in_sizes; (void)n_in; (void)out_size; (void)ws_size;

  unsigned short* wsH = (unsigned short*)d_ws;
  unsigned short* wsL = wsH + 64 * DIM;

  wfrag_kernel<<<64, 256, 0, stream>>>(gw, wsH, wsL);
  router_mfma<<<NROWS / BM, TPB, 0, stream>>>(x, wsH, wsL, gb, mt, outp);
}

// Round 6
// 206.898 us; speedup vs baseline: 1.0709x; 1.0709x over previous
//
#include <hip/hip_runtime.h>
#include <math.h>

// DynamicHybridRouter via bf16-split MFMA (3-term: xh*wh + xh*wl + xl*wh).
// R6: R3-R5 (~78us) were bound by hidden B-frag L2/L3 traffic (512 MB = 1024
// blocks x 512KB re-read) + per-step B latency serialization (replays with x
// L3-resident ran the same 78us -> not HBM-bound). Fix: grid=256 (1 block/CU),
// BM=64, 4 waves split ROWS (16 each) sharing full K. B staged to LDS once per
// block, double-buffered in 4-step chunks (16 barriers) -> B traffic 128 MB and
// off the critical path. x register-prefetched one chunk ahead, issued AFTER
// B-stage loads so the ds_write vmcnt wait leaves x in flight (in-order vmcnt).

#define NROWS 16384
#define DIM   2048
#define NEXP  64
#define BM    64
#define TPB   256
#define CH    4                  // K-steps per chunk (k-span 128)
#define NCH   (DIM / 32 / CH)    // 16 chunks

typedef __attribute__((ext_vector_type(4))) float f32x4;
typedef __attribute__((ext_vector_type(8))) short bf16x8;

// ---- prologue: w [64][2048] f32 -> B-frag-ordered bf16 hi/lo in ws ----
// frag slot = (kstep*4 + t), kstep 0..63, t 0..3: 64 lanes x bf16x8.
// lane's frag: w[e=16t+(lane&15)][k = kstep*32 + (lane>>4)*8 + j], j=0..7.
__global__ void wfrag_kernel(const float* __restrict__ gw,
                             unsigned short* __restrict__ wsH,
                             unsigned short* __restrict__ wsL) {
  int slot  = blockIdx.x * 256 + threadIdx.x;   // 0..16383
  int lane  = slot & 63;
  int t     = (slot >> 6) & 3;
  int kstep = slot >> 8;
  int e  = 16 * t + (lane & 15);
  int k0 = kstep * 32 + (lane >> 4) * 8;
  const float* src = gw + (size_t)e * DIM + k0;
  bf16x8 vh, vl;
#pragma unroll
  for (int j = 0; j < 8; ++j) {
    float w = src[j];
    unsigned u = __float_as_uint(w);
    vh[j] = (short)(u >> 16);
    float hi = __uint_as_float(u & 0xffff0000u);
    float rl = w - hi;
    vl[j] = (short)(__float_as_uint(rl) >> 16);
  }
  ((bf16x8*)wsH)[slot] = vh;
  ((bf16x8*)wsL)[slot] = vl;
}

// ---- main kernel ----
__global__ __launch_bounds__(TPB, 1)
void router_mfma(const float* __restrict__ x,
                 const unsigned short* __restrict__ wsH,
                 const unsigned short* __restrict__ wsL,
                 const float* __restrict__ gb,
                 const int* __restrict__ mat,
                 float* __restrict__ out) {
  // staging: 2 buffers x CH steps x 8 frag-blocks(4 tiles x hi/lo) x 1KB = 64KB
  // reused post-loop as the 64x64 logit slab (16KB).
  __shared__ __align__(16) char lds[2 * CH * 8 * 1024];
  __shared__ float p_a[BM], p_b[BM];
  __shared__ int   p_i[BM], p_j[BM];
  __shared__ int   s_flag;

  const int tid  = threadIdx.x;
  const int wave = tid >> 6;     // row group: rows 16*wave .. +15
  const int lane = tid & 63;
  const int m    = lane & 15;
  const int kg   = lane >> 4;
  const int row0 = blockIdx.x * BM;

  if (tid < 64) {
    unsigned long long b = __ballot(mat[lane] == 0);
    if (lane == 0) s_flag = (b != 0ull) ? 1 : 0;
  }

  f32x4 acc[4];
#pragma unroll
  for (int t = 0; t < 4; ++t) acc[t] = (f32x4)0.0f;

  const bf16x8* wsHf = (const bf16x8*)wsH;
  const bf16x8* wsLf = (const bf16x8*)wsL;

  // wave w stages step st=w of each chunk: 8 units (4 tiles x hi/lo), 1KB each.
  // src slot for chunk c, tile t: (c*CH + wave)*4 + t.
  bf16x8 breg[8];
  const float* xb = x + (size_t)(row0 + 16 * wave + m) * DIM + kg * 8;

  // ---- prologue: stage chunk 0, prefetch x chunk 0 ----
#pragma unroll
  for (int u = 0; u < 8; ++u) {
    int t = u >> 1;
    size_t slot = (size_t)((0 * CH + wave) * 4 + t);
    breg[u] = (u & 1) ? wsLf[slot * 64 + lane] : wsHf[slot * 64 + lane];
  }
  float4 xc[CH][2], xn[CH][2];
#pragma unroll
  for (int st = 0; st < CH; ++st) {
    xc[st][0] = *(const float4*)(xb + st * 32);
    xc[st][1] = *(const float4*)(xb + st * 32 + 4);
  }
#pragma unroll
  for (int u = 0; u < 8; ++u)
    *(bf16x8*)(lds + (wave * 8 + u) * 1024 + lane * 16) = breg[u];
  __syncthreads();

#pragma unroll 1
  for (int c = 0; c < NCH; ++c) {
    const int par = (c & 1) * 32768;
    const bool more = (c + 1 < NCH);
    // 1) B-stage loads for chunk c+1 (oldest outstanding)
    if (more) {
#pragma unroll
      for (int u = 0; u < 8; ++u) {
        int t = u >> 1;
        size_t slot = (size_t)(((c + 1) * CH + wave) * 4 + t);
        breg[u] = (u & 1) ? wsLf[slot * 64 + lane] : wsHf[slot * 64 + lane];
      }
      // 2) x prefetch for chunk c+1 (younger than B-stage loads)
      const float* xp = xb + (c + 1) * (CH * 32);
#pragma unroll
      for (int st = 0; st < CH; ++st) {
        xn[st][0] = *(const float4*)(xp + st * 32);
        xn[st][1] = *(const float4*)(xp + st * 32 + 4);
      }
    }
    // 3) compute chunk c from buf[par] + xc (no vmcnt dependence)
#pragma unroll
    for (int st = 0; st < CH; ++st) {
      bf16x8 bh[4], bl[4];
#pragma unroll
      for (int t = 0; t < 4; ++t) {
        bh[t] = *(const bf16x8*)(lds + par + (st * 8 + 2 * t) * 1024 + lane * 16);
        bl[t] = *(const bf16x8*)(lds + par + (st * 8 + 2 * t + 1) * 1024 + lane * 16);
      }
      bf16x8 ah, al;
#pragma unroll
      for (int q = 0; q < 2; ++q) {
        float4 v = xc[st][q];
        float ff[4] = {v.x, v.y, v.z, v.w};
#pragma unroll
        for (int j = 0; j < 4; ++j) {
          unsigned u = __float_as_uint(ff[j]);
          ah[q * 4 + j] = (short)(u >> 16);
          float hi = __uint_as_float(u & 0xffff0000u);
          float rl = ff[j] - hi;
          al[q * 4 + j] = (short)(__float_as_uint(rl) >> 16);
        }
      }
#pragma unroll
      for (int t = 0; t < 4; ++t) {
        acc[t] = __builtin_amdgcn_mfma_f32_16x16x32_bf16(ah, bh[t], acc[t], 0, 0, 0);
        acc[t] = __builtin_amdgcn_mfma_f32_16x16x32_bf16(ah, bl[t], acc[t], 0, 0, 0);
        acc[t] = __builtin_amdgcn_mfma_f32_16x16x32_bf16(al, bh[t], acc[t], 0, 0, 0);
      }
    }
    // 4) commit staged B(c+1): vmcnt wait covers only the B loads (x is younger)
    if (more) {
      const int par2 = ((c + 1) & 1) * 32768;
#pragma unroll
      for (int u = 0; u < 8; ++u)
        *(bf16x8*)(lds + par2 + (wave * 8 + u) * 1024 + lane * 16) = breg[u];
#pragma unroll
      for (int st = 0; st < CH; ++st) {
        xc[st][0] = xn[st][0];
        xc[st][1] = xn[st][1];
      }
    }
    // 5) one barrier per chunk
    __syncthreads();
  }

  // ---- epilogue: slab reuse (all compute done after final barrier) ----
  // C/D layout: col(lane&15)=expert-in-tile, row=kg*4+reg -> local x-row.
  float* slab = (float*)lds;   // [64 rows][64 experts]
  {
    float gbv[4];
#pragma unroll
    for (int t = 0; t < 4; ++t) gbv[t] = gb[16 * t + m];
#pragma unroll
    for (int t = 0; t < 4; ++t)
#pragma unroll
      for (int reg = 0; reg < 4; ++reg)
        slab[(16 * wave + kg * 4 + reg) * NEXP + 16 * t + m] = acc[t][reg] + gbv[t];
  }
  __syncthreads();

  const int flag = s_flag;

  // per-row routing (threads 0..63; rotated scan spreads LDS banks)
  if (tid < BM) {
    const float* rowp = slab + tid * NEXP;
    if (flag == 0) {
      float m1 = -1e30f, m2 = -1e30f;
      int i1 = 0, i2 = 0;
      for (int ee = 0; ee < NEXP; ++ee) {
        int e = (ee + tid) & (NEXP - 1);
        float v = rowp[e];
        if (v > m1) { m2 = m1; i2 = i1; m1 = v; i1 = e; }
        else if (v > m2) { m2 = v; i2 = e; }
      }
      float t = expf(m2 - m1);
      float pa = 1.0f / (1.0f + t);
      p_a[tid] = pa;
      p_b[tid] = t * pa;
      p_i[tid] = i1;
      p_j[tid] = i2;
    } else {
      float mx = -1e30f;
      for (int ee = 0; ee < NEXP; ++ee)
        mx = fmaxf(mx, rowp[(ee + tid) & (NEXP - 1)]);
      float ssum = 0.0f;
      for (int ee = 0; ee < NEXP; ++ee)
        ssum += expf((rowp[(ee + tid) & (NEXP - 1)] - mx) * 0.5f);  // /T=2
      p_a[tid] = mx;
      p_b[tid] = 1.0f / ssum;
    }
  }
  __syncthreads();

  // output: 64x64 tile = 1024 float4, 4 per thread
#pragma unroll
  for (int i = 0; i < 4; ++i) {
    int q  = tid + i * TPB;
    int r  = q >> 4;
    int e0 = (q & 15) * 4;
    float4 v;
    if (flag == 0) {
      int i1 = p_i[r], i2 = p_j[r];
      float a = p_a[r], b = p_b[r];
      v.x = (e0 + 0 == i1) ? a : (e0 + 0 == i2) ? b : 0.0f;
      v.y = (e0 + 1 == i1) ? a : (e0 + 1 == i2) ? b : 0.0f;
      v.z = (e0 + 2 == i1) ? a : (e0 + 2 == i2) ? b : 0.0f;
      v.w = (e0 + 3 == i1) ? a : (e0 + 3 == i2) ? b : 0.0f;
    } else {
      float mx = p_a[r], inv = p_b[r];
      const float* rowp = slab + r * NEXP + e0;
      v.x = expf((rowp[0] - mx) * 0.5f) * inv;
      v.y = expf((rowp[1] - mx) * 0.5f) * inv;
      v.z = expf((rowp[2] - mx) * 0.5f) * inv;
      v.w = expf((rowp[3] - mx) * 0.5f) * inv;
    }
    *(float4*)(out + (size_t)(row0 + r) * NEXP + e0) = v;
  }
}

extern "C" void kernel_launch(void* const* d_in, const int* in_sizes, int n_in,
                              void* d_out, int out_size, void* d_ws, size_t ws_size,
                              hipStream_t stream) {
  const float* x  = (const float*)d_in[0];
  const float* gw = (const float*)d_in[1];
  const float* gb = (const float*)d_in[2];
  const int*   mt = (const int*)d_in[3];
  float* outp = (float*)d_out;
  (void)in_sizes; (void)n_in; (void)out_size; (void)ws_size;

  unsigned short* wsH = (unsigned short*)d_ws;
  unsigned short* wsL = wsH + 64 * DIM;

  wfrag_kernel<<<64, 256, 0, stream>>>(gw, wsH, wsL);
  router_mfma<<<NROWS / BM, TPB, 0, stream>>>(x, wsH, wsL, gb, mt, outp);
}